// Round 1
// 230.506 us; speedup vs baseline: 1.0180x; 1.0180x over previous
//
#include <hip/hip_runtime.h>
#include <hip/hip_bf16.h>
#include <cmath>
#include <cstdint>

#define NNODES 2048
#define NEDGES 8192
#define NCH 64
#define NHID 64
#define NPATH 34
#define NTASK (NPATH * NCH)   // 2176
#define CGTOT 3436
#define MROW 9984
#define TTOT2 888             // CGT2 rows, per-path 8-aligned
#define EBLK 8                // edges per LDS chunk

#define MI_BYTES ((size_t)NNODES * MROW * 2)          // 40,894,464
#define XT_BYTES ((size_t)NNODES * 16 * NCH * 2)      //  4,194,304
#define OFF_OFF  (MI_BYTES)
#define CUR_OFF  (OFF_OFF + 2052 * 4)
#define PACK_OFF (CUR_OFF + 2048 * 4)
#define ORD_OFF  (PACK_OFF + 8192 * 4)
#define XT_OFF   (ORD_OFF + 2048 * 4)
#define CGP_OFF  (XT_OFF + XT_BYTES)
#define CGP_FLOATS (TTOT2 * 9)                        // 888*8 CGT2 + 888 meta

typedef __attribute__((ext_vector_type(8))) short short8;
typedef __attribute__((ext_vector_type(4))) float floatx4;

// ---------------- path tables (compile-time) ----------------
struct PathTables {
  int l1[NPATH], l2[NPATH], l3[NPATH];
  int cg_off[NPATH], t_off2[NPATH], rank[NPATH];
  int gpaths[2][20], gnp[2], gbase[2], glen[2];
  int cg_total, ttot2, npaths;
};

constexpr PathTables make_tables() {
  PathTables tb{};
  int np = 0;
  for (int a = 0; a < 4; ++a)
    for (int b = 0; b < 4; ++b) {
      int lo = a > b ? a - b : b - a;
      int hi = a + b < 3 ? a + b : 3;
      for (int c = lo; c <= hi; ++c) { tb.l1[np] = a; tb.l2[np] = b; tb.l3[np] = c; ++np; }
    }
  int cg = 0;
  int cnt[4] = {0, 0, 0, 0};
  for (int i = 0; i < np; ++i) {
    tb.cg_off[i] = cg; tb.rank[i] = cnt[tb.l3[i]]++;
    cg += (2 * tb.l1[i] + 1) * (2 * tb.l2[i] + 1) * (2 * tb.l3[i] + 1);
  }
  // group 0: l3 in {0,3}; group 1: l3 in {1,2}; offsets contiguous per group
  int tt2 = 0;
  for (int g = 0; g < 2; ++g) {
    tb.gbase[g] = tt2;
    for (int i = 0; i < np; ++i) {
      int gi = (tb.l3[i] == 0 || tb.l3[i] == 3) ? 0 : 1;
      if (gi != g) continue;
      tb.gpaths[g][tb.gnp[g]++] = i;
      tb.t_off2[i] = tt2;
      int d1 = 2 * tb.l1[i] + 1, d3 = 2 * tb.l3[i] + 1;
      tt2 += ((d1 * d3 + 7) / 8) * 8;
    }
    tb.glen[g] = tt2 - tb.gbase[g];
  }
  tb.cg_total = cg; tb.ttot2 = tt2; tb.npaths = np;
  return tb;
}

constexpr PathTables H_TB = make_tables();
static_assert(H_TB.npaths == NPATH, "npaths");
static_assert(H_TB.cg_total == CGTOT, "cgtot");
static_assert(H_TB.ttot2 == TTOT2, "ttot2");
static_assert(H_TB.gnp[0] == 14 && H_TB.gnp[1] == 20, "gnp");
static_assert(H_TB.gbase[1] == 432 && H_TB.glen[1] == 456, "gsplit");

__constant__ PathTables d_tb = make_tables();

// ---------------- NumPy legacy RandomState(1234) reproduction (host) ----------------
namespace {
struct MT19937 {
  uint32_t mt[624]; int mti; bool has_g; double gval;
  void seed(uint32_t s) {
    for (int i = 0; i < 624; ++i) { mt[i] = s; s = 1812433253u * (s ^ (s >> 30)) + (uint32_t)i + 1u; }
    mti = 624; has_g = false; gval = 0.0;
  }
  uint32_t next() {
    if (mti >= 624) {
      for (int i = 0; i < 624; ++i) {
        uint32_t y = (mt[i] & 0x80000000u) | (mt[(i + 1) % 624] & 0x7fffffffu);
        mt[i] = mt[(i + 397) % 624] ^ (y >> 1) ^ ((y & 1u) ? 0x9908b0dfu : 0u);
      }
      mti = 0;
    }
    uint32_t y = mt[mti++];
    y ^= y >> 11; y ^= (y << 7) & 0x9d2c5680u; y ^= (y << 15) & 0xefc60000u; y ^= y >> 18;
    return y;
  }
  double rdbl() {
    uint32_t a = next() >> 5, b = next() >> 6;
    return ((double)a * 67108864.0 + (double)b) / 9007199254740992.0;
  }
  double gauss() {
    if (has_g) { has_g = false; return gval; }
    double x1, x2, r2;
    do {
      x1 = 2.0 * rdbl() - 1.0;
      x2 = 2.0 * rdbl() - 1.0;
      r2 = x1 * x1 + x2 * x2;
    } while (r2 >= 1.0 || r2 == 0.0);
    double f = std::sqrt(-2.0 * std::log(r2) / r2);
    gval = f * x1; has_g = true;
    return f * x2;
  }
};

float host_pack[CGP_FLOATS];
float* g_cg_dev = nullptr;
bool g_cg_ok = false;

struct CGInit {
  CGInit() {
    static float cg[CGTOT];
    MT19937 g; g.seed(1234u);
    int idx = 0;
    for (int i = 0; i < NPATH; ++i) {
      int d1 = 2 * H_TB.l1[i] + 1, d2 = 2 * H_TB.l2[i] + 1, d3 = 2 * H_TB.l3[i] + 1;
      int sz = d1 * d2 * d3;
      for (int k = 0; k < sz; ++k) cg[idx++] = (float)(g.gauss() * 0.2);
    }
    const int ybase[4] = {0, 1, 4, 9};
    for (int k = 0; k < CGP_FLOATS; ++k) host_pack[k] = 0.f;
    for (int i = 0; i < NPATH; ++i) {
      int d1 = 2 * H_TB.l1[i] + 1, d2 = 2 * H_TB.l2[i] + 1, d3 = 2 * H_TB.l3[i] + 1;
      for (int l = 0; l < d1; ++l)
        for (int n3 = 0; n3 < d3; ++n3) {
          int tt2 = H_TB.t_off2[i] + l * d3 + n3;
          for (int m = 0; m < d2; ++m)
            host_pack[tt2 * 8 + m] = cg[H_TB.cg_off[i] + l * d2 * d3 + m * d3 + n3];
          host_pack[TTOT2 * 8 + tt2] = (float)ybase[H_TB.l2[i]];
        }
    }
    (void)hipHostRegister(host_pack, sizeof(host_pack), hipHostRegisterDefault);
    void* p = nullptr;
    if (hipMalloc(&p, sizeof(host_pack)) == hipSuccess && p) {
      if (hipMemcpy(p, host_pack, sizeof(host_pack), hipMemcpyHostToDevice) == hipSuccess) {
        float back = -1.f;
        if (hipMemcpy(&back, (float*)p + (CGP_FLOATS - 1), sizeof(float),
                      hipMemcpyDeviceToHost) == hipSuccess && back == host_pack[CGP_FLOATS - 1]) {
          g_cg_dev = (float*)p;
          g_cg_ok = true;
        }
      }
    }
  }
} cg_init_instance;
}  // namespace

__device__ __forceinline__ float bf2f(unsigned short u) {
  union { unsigned int i; float f; } v; v.i = ((unsigned int)u) << 16; return v.f;
}
__device__ __forceinline__ unsigned short f2bf(float f) {
  __hip_bfloat16 h = __float2bfloat16(f);
  union { __hip_bfloat16 h; unsigned short u; } v; v.h = h; return v.u;
}

// ---------------- kernel A: CSR degrees + prefix + degree-descending order ----------------
__global__ __launch_bounds__(1024) void scan_kernel(
    const int* __restrict__ edge_index, int* __restrict__ off, int* __restrict__ cursor,
    int* __restrict__ order)
{
  __shared__ int ldeg[NNODES];
  __shared__ int csum[1024];
  __shared__ int hist[64];
  const int t = threadIdx.x;
  for (int i = t; i < NNODES; i += 1024) ldeg[i] = 0;
  __syncthreads();
  const int* __restrict__ dsts = edge_index + NEDGES;
  for (int e = t; e < NEDGES; e += 1024) atomicAdd(&ldeg[dsts[e]], 1);
  __syncthreads();
  const int l0 = ldeg[2 * t], l1 = ldeg[2 * t + 1];
  const int s = l0 + l1;
  csum[t] = s;
  __syncthreads();
  for (int o = 1; o < 1024; o <<= 1) {
    int v = (t >= o) ? csum[t - o] : 0;
    __syncthreads();
    csum[t] += v;
    __syncthreads();
  }
  int run = csum[t] - s;
  off[2 * t] = run; cursor[2 * t] = run;
  off[2 * t + 1] = run + l0; cursor[2 * t + 1] = run + l0;
  if (t == 0) off[NNODES] = NEDGES;
  // degree-descending order (64 buckets)
  if (t < 64) hist[t] = 0;
  __syncthreads();
  for (int i = t; i < NNODES; i += 1024) {
    int d = ldeg[i]; d = d > 63 ? 63 : d;
    atomicAdd(&hist[63 - d], 1);
  }
  __syncthreads();
  if (t == 0) { int r2 = 0; for (int b = 0; b < 64; ++b) { int c = hist[b]; hist[b] = r2; r2 += c; } }
  __syncthreads();
  for (int i = t; i < NNODES; i += 1024) {
    int d = ldeg[i]; d = d > 63 ? 63 : d;
    int pos = atomicAdd(&hist[63 - d], 1);
    order[pos] = i;
  }
}

// ---------------- kernel B: CSR fill + xT build ----------------
__global__ __launch_bounds__(256) void fill_xt_kernel(
    const int* __restrict__ edge_index, int* __restrict__ cursor, int* __restrict__ pack,
    const float* __restrict__ x0, const float* __restrict__ x1,
    const float* __restrict__ x2, const float* __restrict__ x3,
    __hip_bfloat16* __restrict__ xT)
{
  const int b = blockIdx.x;
  const int t = threadIdx.x;
  if (b < 32) {
    const int e = b * 256 + t;
    const int d = edge_index[NEDGES + e];
    const int s = edge_index[e];
    const int pos = atomicAdd(&cursor[d], 1);
    pack[pos] = e | (s << 13);
  } else {
    const int n = b - 32;
    for (int idx = t; idx < 1024; idx += 256) {
      const int j = idx >> 6, c = idx & 63;   // j wave-uniform
      const float* src; int d1, m;
      if (j < 1)      { src = x0; d1 = 1; m = j; }
      else if (j < 4) { src = x1; d1 = 3; m = j - 1; }
      else if (j < 9) { src = x2; d1 = 5; m = j - 4; }
      else            { src = x3; d1 = 7; m = j - 9; }
      const float v = src[((size_t)n * NCH + c) * d1 + m];
      xT[((size_t)n * 16 + j) * NCH + c] = __float2bfloat16(v);
    }
  }
}

// ---------------- kernel 1: per-node TP, in-kernel T, LDS-staged ----------------
// xs: LDS-staged xT rows for the chunk's edges, layout [EBLK][16][64] bf16.
// wv_: per-task ws values, prefetched one task ahead by the caller (registers).
template <int D1, int D3>
__device__ __forceinline__ void tp_task_run(
    int c, int toff_l, int rank, int nb,
    const float (*Ts)[456], const unsigned short* xs, const float* wv_,
    int n, bool first, __hip_bfloat16* __restrict__ m_out)
{
  constexpr int Kc = (D3 == 1) ? 256 : (D3 == 3) ? 576 : (D3 == 5) ? 704 : 640;
  constexpr int Rc = (D3 == 1) ? 0 : (D3 == 3) ? 256 : (D3 == 5) ? 1984 : 5504;
  constexpr int JB = (D1 == 1) ? 0 : (D1 == 3) ? 1 : (D1 == 5) ? 4 : 9;

  float acc[D3];
#pragma unroll
  for (int m = 0; m < D3; ++m) acc[m] = 0.f;

  // fully unrolled edge loop: compile-time indices (no scratch), deep pipelining
#pragma unroll
  for (int ei = 0; ei < EBLK; ++ei) {
    if (ei >= nb) break;
    const unsigned short* xr = xs + (ei * 16 + JB) * 64 + c;   // LDS, lanes=c: conflict-free
    const float* Tp = &Ts[ei][toff_l];                          // LDS, wave-uniform: broadcast
    float u[D3];
#pragma unroll
    for (int m = 0; m < D3; ++m) u[m] = 0.f;
#pragma unroll
    for (int l = 0; l < D1; ++l) {
      const float xv = bf2f(xr[l * 64]);
#pragma unroll
      for (int m = 0; m < D3; ++m) u[m] += xv * Tp[l * D3 + m];
    }
#pragma unroll
    for (int m = 0; m < D3; ++m) acc[m] += wv_[ei] * u[m];
  }

  __hip_bfloat16* mo = m_out + (size_t)n * MROW + Rc + rank * NCH + c;
  if (first) {
#pragma unroll
    for (int m = 0; m < D3; ++m) mo[m * Kc] = __float2bfloat16(acc[m]);
  } else {
#pragma unroll
    for (int m = 0; m < D3; ++m)
      mo[m * Kc] = __float2bfloat16(__bfloat162float(mo[m * Kc]) + acc[m]);
  }
}

__global__ __launch_bounds__(256) void tp_node_kernel(
    const float* __restrict__ y0, const float* __restrict__ y1,
    const float* __restrict__ y2, const float* __restrict__ y3,
    const float* __restrict__ ws, const unsigned short* __restrict__ xT,
    const float* __restrict__ cg_pack,
    const int* __restrict__ off, const int* __restrict__ pack,
    const int* __restrict__ order,
    __hip_bfloat16* __restrict__ m_out)
{
  __shared__ float Ts[EBLK][456];            // 14.25 KB
  __shared__ float y_s[EBLK][18];            // 0.56 KB
  __shared__ int epk[EBLK];
  __shared__ unsigned short xs[EBLK][16][64]; // 16 KB — staged xT rows for chunk edges

  const int bid = blockIdx.x;
  const int n = order[bid >> 1];
  const int g = bid & 1;
  const int t = threadIdx.x;
  const int beg = off[n];
  const int cnt = off[n + 1] - beg;
  const int gbase = d_tb.gbase[g];
  const int glen  = d_tb.glen[g];
  const int ntask = d_tb.gnp[g] << 6;
  const float* __restrict__ metaf = cg_pack + TTOT2 * 8;

  for (int base = 0; base == 0 || base < cnt; base += EBLK) {
    int nb = cnt - base;
    nb = nb < 0 ? 0 : (nb > EBLK ? EBLK : nb);
    if (t < nb) epk[t] = pack[beg + base + t];
    if (t >= 64 && t < 64 + 2 * EBLK) y_s[(t - 64) >> 1][16 + (t & 1)] = 0.f;
    __syncthreads();
    // stage y for the chunk's edges
    if (t < nb * 16) {
      const int ei = t >> 4, j = t & 15;
      const int e = epk[ei] & 8191;
      float v;
      if (j < 1)      v = y0[e];
      else if (j < 4) v = y1[e * 3 + (j - 1)];
      else if (j < 9) v = y2[e * 5 + (j - 4)];
      else            v = y3[e * 7 + (j - 9)];
      y_s[ei][j] = v;
    }
    // stage xT rows into LDS: 2 KB per edge, 8 loads in flight, coalesced uint2
    {
      uint2 tmp[EBLK];
#pragma unroll
      for (int ei = 0; ei < EBLK; ++ei) {
        const int s = (epk[ei] >> 13) & 2047;   // mask keeps stale values in-range
        const uint2* __restrict__ src = (const uint2*)(xT + ((size_t)s << 10));
        if (ei < nb) tmp[ei] = src[t];
      }
#pragma unroll
      for (int ei = 0; ei < EBLK; ++ei)
        if (ei < nb) *((uint2*)(&xs[ei][0][0]) + t) = tmp[ei];
    }
    __syncthreads();
    // compute T in LDS: Ts[ei][j] = sum_m CGT2[gbase+j][m] * y[ei][yb+m]
    // CG loads hoisted out of the ei loop (were re-fetched xnb before)
    for (int j = t; j < glen; j += 256) {
      const int tt2 = gbase + j;
      const float4 a = *(const float4*)(cg_pack + tt2 * 8);
      const float4 c4 = *(const float4*)(cg_pack + tt2 * 8 + 4);
      const int yb = (int)metaf[tt2];
      for (int ei = 0; ei < nb; ++ei) {
        const float* yy = &y_s[ei][yb];
        Ts[ei][j] = a.x * yy[0] + a.y * yy[1] + a.z * yy[2] + a.w * yy[3]
                  + c4.x * yy[4] + c4.y * yy[5] + c4.z * yy[6] + c4.w * yy[7];
      }
    }
    __syncthreads();

    const bool first = (base == 0);
    const int c = t & 63;
    // task loop with one-task-ahead ws prefetch (named reg arrays: no scratch)
    float wcur[EBLK], wnxt[EBLK];
    if (t < ntask) {
      const int i0 = d_tb.gpaths[g][t >> 6];
      const int wc0 = (i0 << 6) | (t & 63);
#pragma unroll
      for (int ei = 0; ei < EBLK; ++ei)
        wcur[ei] = (ei < nb) ? ws[(size_t)(epk[ei] & 8191) * NTASK + wc0] : 0.f;
    }
    for (int k = 0; k * 256 + t < ntask; ++k) {
      const int tl = k * 256 + t;
      const int tln = tl + 256;
      const bool more = tln < ntask;
      if (more) {   // issue next task's ws loads before this task's compute
        const int in = d_tb.gpaths[g][tln >> 6];
        const int wcn = (in << 6) | (tln & 63);
#pragma unroll
        for (int ei = 0; ei < EBLK; ++ei)
          wnxt[ei] = (ei < nb) ? ws[(size_t)(epk[ei] & 8191) * NTASK + wcn] : 0.f;
      }
      const int i = d_tb.gpaths[g][tl >> 6];   // wave-uniform
      const int toff_l = d_tb.t_off2[i] - gbase;
      const int rk = d_tb.rank[i];
      const int code = d_tb.l1[i] * 4 + d_tb.l3[i];
      switch (code) {
        case  0: tp_task_run<1,1>(c, toff_l, rk, nb, Ts, &xs[0][0][0], wcur, n, first, m_out); break;
        case  1: tp_task_run<1,3>(c, toff_l, rk, nb, Ts, &xs[0][0][0], wcur, n, first, m_out); break;
        case  2: tp_task_run<1,5>(c, toff_l, rk, nb, Ts, &xs[0][0][0], wcur, n, first, m_out); break;
        case  3: tp_task_run<1,7>(c, toff_l, rk, nb, Ts, &xs[0][0][0], wcur, n, first, m_out); break;
        case  4: tp_task_run<3,1>(c, toff_l, rk, nb, Ts, &xs[0][0][0], wcur, n, first, m_out); break;
        case  5: tp_task_run<3,3>(c, toff_l, rk, nb, Ts, &xs[0][0][0], wcur, n, first, m_out); break;
        case  6: tp_task_run<3,5>(c, toff_l, rk, nb, Ts, &xs[0][0][0], wcur, n, first, m_out); break;
        case  7: tp_task_run<3,7>(c, toff_l, rk, nb, Ts, &xs[0][0][0], wcur, n, first, m_out); break;
        case  8: tp_task_run<5,1>(c, toff_l, rk, nb, Ts, &xs[0][0][0], wcur, n, first, m_out); break;
        case  9: tp_task_run<5,3>(c, toff_l, rk, nb, Ts, &xs[0][0][0], wcur, n, first, m_out); break;
        case 10: tp_task_run<5,5>(c, toff_l, rk, nb, Ts, &xs[0][0][0], wcur, n, first, m_out); break;
        case 11: tp_task_run<5,7>(c, toff_l, rk, nb, Ts, &xs[0][0][0], wcur, n, first, m_out); break;
        case 12: tp_task_run<7,1>(c, toff_l, rk, nb, Ts, &xs[0][0][0], wcur, n, first, m_out); break;
        case 13: tp_task_run<7,3>(c, toff_l, rk, nb, Ts, &xs[0][0][0], wcur, n, first, m_out); break;
        case 14: tp_task_run<7,5>(c, toff_l, rk, nb, Ts, &xs[0][0][0], wcur, n, first, m_out); break;
        default: tp_task_run<7,7>(c, toff_l, rk, nb, Ts, &xs[0][0][0], wcur, n, first, m_out); break;
      }
      if (more) {
#pragma unroll
        for (int ei = 0; ei < EBLK; ++ei) wcur[ei] = wnxt[ei];
      }
    }
    __syncthreads();
  }
}

// ---------------- kernel 2: fused per-l3 linear — MFMA bf16 ----------------
template <int D3, int K, int ROFF>
__device__ __forceinline__ void lin_mfma_body(
    int blk, const unsigned short* __restrict__ mu, const float* __restrict__ wl,
    float* __restrict__ out, unsigned short (*A_s)[72], unsigned short (*W_s)[72])
{
  const int t = threadIdx.x;
  const int wv = t >> 6;
  const int lane = t & 63;
  const int idx16 = lane & 15;
  const int quad = lane >> 4;
  const int r0 = blk * 64;

  floatx4 acc[4] = {{0.f,0.f,0.f,0.f},{0.f,0.f,0.f,0.f},{0.f,0.f,0.f,0.f},{0.f,0.f,0.f,0.f}};

  for (int k0 = 0; k0 < K; k0 += 64) {
    for (int idx = t; idx < 512; idx += 256) {
      const int rr = idx >> 3, ck = (idx & 7) * 8;
      const int r = r0 + rr;
      const int nn = r / D3, mm = r - nn * D3;
      const uint4 v = *(const uint4*)(mu + (size_t)nn * MROW + ROFF + mm * K + k0 + ck);
      *(uint4*)&A_s[rr][ck] = v;
    }
    {
      const int h = t & 63, kg = t >> 6;
      unsigned short tmp[16];
#pragma unroll
      for (int j = 0; j < 16; ++j)
        tmp[j] = f2bf(wl[(size_t)(k0 + kg * 16 + j) * 64 + h]);
      *(uint4*)&W_s[h][kg * 16]     = *(const uint4*)&tmp[0];
      *(uint4*)&W_s[h][kg * 16 + 8] = *(const uint4*)&tmp[8];
    }
    __syncthreads();
#pragma unroll
    for (int ks = 0; ks < 2; ++ks) {
      const int kb = ks * 32 + quad * 8;
      const short8 af = *(const short8*)&A_s[wv * 16 + idx16][kb];
#pragma unroll
      for (int nt = 0; nt < 4; ++nt) {
        const short8 bf = *(const short8*)&W_s[nt * 16 + idx16][kb];
        acc[nt] = __builtin_amdgcn_mfma_f32_16x16x32_bf16(af, bf, acc[nt], 0, 0, 0);
      }
    }
    __syncthreads();
  }

#pragma unroll
  for (int nt = 0; nt < 4; ++nt) {
    const int h = nt * 16 + idx16;
#pragma unroll
    for (int r = 0; r < 4; ++r) {
      const int row = r0 + wv * 16 + quad * 4 + r;
      const int nn = row / D3, mm = row - nn * D3;
      out[((size_t)nn * NHID + h) * D3 + mm] = acc[nt][r];
    }
  }
}

__global__ __launch_bounds__(256) void lin_fused_kernel(
    const unsigned short* __restrict__ mu,
    const float* __restrict__ wl0, const float* __restrict__ wl1,
    const float* __restrict__ wl2, const float* __restrict__ wl3,
    float* __restrict__ out)
{
  __shared__ unsigned short A_s[64][72];
  __shared__ unsigned short W_s[64][72];
  const int b = blockIdx.x;
  if (b < 32)       lin_mfma_body<1, 256, 0>   (b,       mu, wl0, out,           A_s, W_s);
  else if (b < 128) lin_mfma_body<3, 576, 256> (b - 32,  mu, wl1, out + 131072,  A_s, W_s);
  else if (b < 288) lin_mfma_body<5, 704, 1984>(b - 128, mu, wl2, out + 524288,  A_s, W_s);
  else              lin_mfma_body<7, 640, 5504>(b - 288, mu, wl3, out + 1179648, A_s, W_s);
}

// ---------------- launch ----------------
extern "C" void kernel_launch(void* const* d_in, const int* in_sizes, int n_in,
                              void* d_out, int out_size, void* d_ws, size_t ws_size,
                              hipStream_t stream) {
  const float* x0  = (const float*)d_in[0];
  const float* y0  = (const float*)d_in[1];
  const float* wl0 = (const float*)d_in[2];
  const float* x1  = (const float*)d_in[3];
  const float* y1  = (const float*)d_in[4];
  const float* wl1 = (const float*)d_in[5];
  const float* x2  = (const float*)d_in[6];
  const float* y2  = (const float*)d_in[7];
  const float* wl2 = (const float*)d_in[8];
  const float* x3  = (const float*)d_in[9];
  const float* y3  = (const float*)d_in[10];
  const float* wl3 = (const float*)d_in[11];
  const float* ws  = (const float*)d_in[12];
  const int* edge_index = (const int*)d_in[13];
  float* out = (float*)d_out;

  __hip_bfloat16* m_i = (__hip_bfloat16*)d_ws;
  int* csr_off = (int*)((char*)d_ws + OFF_OFF);
  int* cursor  = (int*)((char*)d_ws + CUR_OFF);
  int* pack    = (int*)((char*)d_ws + PACK_OFF);
  int* order   = (int*)((char*)d_ws + ORD_OFF);
  __hip_bfloat16* xT = (__hip_bfloat16*)((char*)d_ws + XT_OFF);

  const float* cg_pack;
  if (g_cg_ok) {
    cg_pack = g_cg_dev;
  } else {
    float* cg_ws = (float*)((char*)d_ws + CGP_OFF);
    hipMemcpyAsync(cg_ws, host_pack, sizeof(host_pack), hipMemcpyHostToDevice, stream);
    cg_pack = cg_ws;
  }

  scan_kernel<<<1, 1024, 0, stream>>>(edge_index, csr_off, cursor, order);
  fill_xt_kernel<<<32 + NNODES, 256, 0, stream>>>(edge_index, cursor, pack,
                                                  x0, x1, x2, x3, xT);
  tp_node_kernel<<<2 * NNODES, 256, 0, stream>>>(y0, y1, y2, y3, ws,
                                                 (const unsigned short*)xT, cg_pack,
                                                 csr_off, pack, order, m_i);
  lin_fused_kernel<<<512, 256, 0, stream>>>((const unsigned short*)m_i,
                                            wl0, wl1, wl2, wl3, out);
}